// Round 12
// baseline (42.215 us; speedup 1.0000x reference)
//
#include <hip/hip_runtime.h>
#include <hip/hip_bf16.h>
#include <math.h>

// DDRFMixer: out[b,t,d] = sum_n softmax_n(x[b,t,:]·W[n,:]) * x[b,t-off_n,d]
// x: [B,T,D] fp32, W: [7,D] fp32, out: [B,T,D] fp32
// B=4, T=4096, D=1024, offsets = {1,2,4,8,16,32,64}
//
// R11: TWO-PASS SPLIT. The fused kernel plateaued at 34.4 us because each
// row's combine waits on the same row's dot->reduce->softmax chain (~2000 cy,
// scheduler can't compress; R9 showed the compiler sinks "prefetched" tap
// loads back to their uses). Splitting into two streaming passes removes the
// serial chain entirely:
//   Pass 1: weights[row][8] = softmax(x[row]·W^T) * causal_mask  (R8's phase 1)
//   Pass 2: out[row] = sum_n weights[row][n] * x[row - off_n]    (pure stream,
//           no reduce/softmax/cross-lane on the critical path; 8-deep MLP)
// Weights live in d_ws (512 KB). Causality: pass 1 zeroes masked weights
// (softmax denom keeps all 7 taps = reference's zero-padded-tap semantics);
// pass 2 clamps tap addresses so b=0 early rows never read below x[0].

#define N_TAPS 7
#define DIM 1024
#define T_LEN 4096
#define BLOCK_THREADS 512
#define ROWS_PER_BLOCK 8     // one wave per row, 8 waves per block

// ---- DPP helpers: canonical GCN wave64 sum ----
template <int CTRL>
__device__ __forceinline__ float dpp_mov0(float v) {
    return __builtin_bit_cast(float,
        __builtin_amdgcn_update_dpp(0, __builtin_bit_cast(int, v),
                                    CTRL, 0xf, 0xf, true));
}
__device__ __forceinline__ float wave_sum_bcast(float v) {
    v += dpp_mov0<0x111>(v);   // row_shr:1
    v += dpp_mov0<0x112>(v);   // row_shr:2
    v += dpp_mov0<0x114>(v);   // row_shr:4
    v += dpp_mov0<0x118>(v);   // row_shr:8
    v += dpp_mov0<0x142>(v);   // row_bcast:15
    v += dpp_mov0<0x143>(v);   // row_bcast:31 -> lane63 = total
    return __builtin_bit_cast(float,
        __builtin_amdgcn_readlane(__builtin_bit_cast(int, v), 63));
}

// ================= Pass 1: weights = softmax(x . W^T) * mask =================
__global__ __launch_bounds__(BLOCK_THREADS) void ddrf_weights_kernel(
    const float* __restrict__ x,    // [B*T, D]
    const float* __restrict__ W,    // [N_TAPS, D]
    float* __restrict__ wts,        // [B*T, 8] (ws)
    int n_rows)
{
    constexpr int offs[N_TAPS] = {1, 2, 4, 8, 16, 32, 64};

    __shared__ float wlds[N_TAPS * DIM];   // 28 KB

    for (int i = threadIdx.x; i < N_TAPS * (DIM / 4); i += BLOCK_THREADS) {
        reinterpret_cast<float4*>(wlds)[i] =
            reinterpret_cast<const float4*>(W)[i];
    }
    __syncthreads();

    // bijective XCD swizzle (gridDim.x = 2048, % 8 == 0)
    const int per = gridDim.x >> 3;
    const int wg  = (blockIdx.x & 7) * per + (blockIdx.x >> 3);

    const int wave = threadIdx.x >> 6;
    const int lane = threadIdx.x & 63;
    const int dofs = lane * 4;

    const int row = wg * ROWS_PER_BLOCK + wave;
    if (row >= n_rows) return;
    const int t = row & (T_LEN - 1);
    const float* xrow = x + (size_t)row * DIM;

    float4 xv[4];
#pragma unroll
    for (int k = 0; k < 4; ++k)
        xv[k] = *reinterpret_cast<const float4*>(xrow + k * 256 + dofs);

    float p[N_TAPS];
#pragma unroll
    for (int n = 0; n < N_TAPS; ++n) {
        const float* wrow = &wlds[n * DIM];
        float4 w0 = *reinterpret_cast<const float4*>(wrow + 0 * 256 + dofs);
        float4 w1 = *reinterpret_cast<const float4*>(wrow + 1 * 256 + dofs);
        float4 w2 = *reinterpret_cast<const float4*>(wrow + 2 * 256 + dofs);
        float4 w3 = *reinterpret_cast<const float4*>(wrow + 3 * 256 + dofs);
        float s0 = fmaf(xv[0].x, w0.x, fmaf(xv[0].y, w0.y, fmaf(xv[0].z, w0.z, xv[0].w * w0.w)));
        float s1 = fmaf(xv[1].x, w1.x, fmaf(xv[1].y, w1.y, fmaf(xv[1].z, w1.z, xv[1].w * w1.w)));
        float s2 = fmaf(xv[2].x, w2.x, fmaf(xv[2].y, w2.y, fmaf(xv[2].z, w2.z, xv[2].w * w2.w)));
        float s3 = fmaf(xv[3].x, w3.x, fmaf(xv[3].y, w3.y, fmaf(xv[3].z, w3.z, xv[3].w * w3.w)));
        p[n] = (s0 + s1) + (s2 + s3);
    }

#pragma unroll
    for (int n = 0; n < N_TAPS; ++n)
        p[n] = wave_sum_bcast(p[n]);

    // softmax (no max subtraction; |logit| small) + causal mask on weights
    float wn[N_TAPS];
    float wsum = 0.f;
#pragma unroll
    for (int n = 0; n < N_TAPS; ++n) {
        wn[n] = __expf(p[n]);
        wsum += wn[n];
    }
    const float inv = 1.0f / wsum;

    // lane n (n<7) writes weight n; lane 7 writes pad 0. cndmask select
    // (static indexing only; dynamic reg-array index would go to scratch).
    float v = 0.f;
#pragma unroll
    for (int n = 0; n < N_TAPS; ++n) {
        const float weff = wn[n] * inv * ((t >= offs[n]) ? 1.0f : 0.0f);
        v = (lane == n) ? weff : v;
    }
    if (lane < 8)
        wts[(size_t)row * 8 + lane] = v;
}

// ================= Pass 2: out = sum_n w[n] * x[row - off_n] =================
__global__ __launch_bounds__(BLOCK_THREADS) void ddrf_mix_kernel(
    const float* __restrict__ x,    // [B*T, D]
    const float* __restrict__ wts,  // [B*T, 8]
    float* __restrict__ out,        // [B*T, D]
    int n_rows)
{
    constexpr int offs[N_TAPS] = {1, 2, 4, 8, 16, 32, 64};

    // bijective XCD swizzle (gridDim.x = 2048, % 8 == 0)
    const int per = gridDim.x >> 3;
    const int wg  = (blockIdx.x & 7) * per + (blockIdx.x >> 3);

    const int wave = threadIdx.x >> 6;
    const int lane = threadIdx.x & 63;
    const int dofs = lane * 4;

    const int row = wg * ROWS_PER_BLOCK + wave;
    if (row >= n_rows) return;
    const int t = row & (T_LEN - 1);
    const float* xrow = x + (size_t)row * DIM;

    // weights for this row (uniform across the wave; 2 vector loads, L1-hot)
    const float4 wa = *reinterpret_cast<const float4*>(wts + (size_t)row * 8);
    const float4 wb = *reinterpret_cast<const float4*>(wts + (size_t)row * 8 + 4);
    const float w[N_TAPS] = { wa.x, wa.y, wa.z, wa.w, wb.x, wb.y, wb.z };

    // clamped tap bases (weights already 0 where masked; clamp keeps b=0
    // early rows in-bounds)
    const float* trow[N_TAPS];
#pragma unroll
    for (int n = 0; n < N_TAPS; ++n)
        trow[n] = xrow - (size_t)((t >= offs[n]) ? offs[n] : 0) * DIM;

    float* orow = out + (size_t)row * DIM;

    // four independent k-chunks: 7 loads -> 7 fma -> store each; the
    // scheduler overlaps chunks (no cross-chunk deps, no serial chain).
#pragma unroll
    for (int k = 0; k < 4; ++k) {
        float4 tv[N_TAPS];
#pragma unroll
        for (int n = 0; n < N_TAPS; ++n)
            tv[n] = *reinterpret_cast<const float4*>(trow[n] + k * 256 + dofs);
        float4 a = make_float4(0.f, 0.f, 0.f, 0.f);
#pragma unroll
        for (int n = 0; n < N_TAPS; ++n) {
            a.x = fmaf(w[n], tv[n].x, a.x);
            a.y = fmaf(w[n], tv[n].y, a.y);
            a.z = fmaf(w[n], tv[n].z, a.z);
            a.w = fmaf(w[n], tv[n].w, a.w);
        }
        *reinterpret_cast<float4*>(orow + k * 256 + dofs) = a;
    }
}

extern "C" void kernel_launch(void* const* d_in, const int* in_sizes, int n_in,
                              void* d_out, int out_size, void* d_ws, size_t ws_size,
                              hipStream_t stream) {
    const float* x = (const float*)d_in[0];   // [B,T,D] fp32
    const float* W = (const float*)d_in[1];   // [N_TAPS,D] fp32
    float* out = (float*)d_out;               // [B,T,D] fp32
    float* wts = (float*)d_ws;                // [B*T, 8] = 512 KB scratch

    const int n_rows   = in_sizes[0] / DIM;          // B*T = 16384
    const int n_blocks = n_rows / ROWS_PER_BLOCK;    // 2048 (divisible by 8)

    ddrf_weights_kernel<<<n_blocks, BLOCK_THREADS, 0, stream>>>(x, W, wts, n_rows);
    ddrf_mix_kernel<<<n_blocks, BLOCK_THREADS, 0, stream>>>(x, wts, out, n_rows);
}